// Round 3
// baseline (846.746 us; speedup 1.0000x reference)
//
#include <hip/hip_runtime.h>
#include <math.h>

// DomainTransformFilter on [8,3,1024,1024] f32.
// 3 iterations of {61-tap horizontal Gaussian, 61-tap vertical Gaussian},
// replicate padding, sigma = 10/20/40 (all ks=61). Edge-weight multiplies
// s = w/(w+1e-8) differ from 1.0 by <7.4e-8 and are dropped (validated:
// absmax 3.9e-3 from fp32 ordering only, threshold ~1.1e-2).
//
// Round-3 structure: LDS-free everywhere. Stage the whole per-thread window
// into a compile-time-indexed register array (one burst of independent
// loads), then run the proven fully-unrolled 76-step x 16-acc FMA loop.
// No barriers, no LDS occupancy cap; waves free-run.
//  - hconv: per-block working set 16 rows x 316 cols ~= 20 KB -> L1-resident;
//    window = 20 aligned float4 loads (edge clamp branch, edge blocks only).
//  - vconv: lanes span x -> every row load is a coalesced 256 B wave read;
//    row address is wave-uniform (SALU). XCD-chunked decode keeps each
//    256-col x 1024-row strip (1 MB) inside one XCD's private L2, so the
//    4.75x vertical halo re-read is an L2 hit (proven: FETCH 138 MB in r1).

#define HH 1024
#define WW 1024
#define BB 8
#define CC 3
#define KS 61
#define HK 30

struct GW { float w[KS]; };   // by value -> kernarg -> SGPR-resident weights

// ---------------------------------------------------------------------------
// Horizontal conv. Thread = 16 consecutive outputs of one row.
// Block 256 thr = 16 rows x 16 segments (256 out cols). Grid flat 6144,
// XCD-chunked (y-strips fastest within an XCD).
// ---------------------------------------------------------------------------
__global__ __launch_bounds__(256) void hconv(const float* __restrict__ in,
                                             float* __restrict__ out, GW g) {
    const int f   = blockIdx.x;            // 0..6143
    const int c   = f & 7;                 // XCD (dispatch round-robin)
    const int idx = f >> 3;                // 0..767
    const int w0  = c * 768 + idx;         // work id, y-strip fastest
    const int yb  = w0 & 63;               // 64 strips of 16 rows
    const int r1  = w0 >> 6;
    const int xc  = r1 & 3;                // 4 chunks of 256 cols
    const int bc  = r1 >> 2;               // 0..23

    const int seg = threadIdx.x & 15;
    const int row = threadIdx.x >> 4;
    const int y   = yb * 16 + row;
    const int X   = xc * 256 + seg * 16;   // first output col
    const int x0  = X - 32;                // float4-aligned window start

    const float* __restrict__ srow = in + ((size_t)bc * HH + y) * WW;

    // stage window [X-32, X+48) = 80 floats = 20 float4 loads
    float v[80];
    #pragma unroll
    for (int m = 0; m < 20; ++m) {
        const int gx = x0 + 4 * m;
        float4 t;
        if (gx >= 0 && gx <= WW - 4) {
            t = *(const float4*)(srow + gx);
        } else {                           // replicate pad (edge blocks only)
            const int a0 = min(max(gx    , 0), WW - 1);
            const int a1 = min(max(gx + 1, 0), WW - 1);
            const int a2 = min(max(gx + 2, 0), WW - 1);
            const int a3 = min(max(gx + 3, 0), WW - 1);
            t = make_float4(srow[a0], srow[a1], srow[a2], srow[a3]);
        }
        v[4 * m + 0] = t.x; v[4 * m + 1] = t.y;
        v[4 * m + 2] = t.z; v[4 * m + 3] = t.w;
    }

    float acc[16];
    #pragma unroll
    for (int i = 0; i < 16; ++i) acc[i] = 0.f;

    // input x = x0 + (j+2) = X - 30 + j ; output i tap t = j - i
    #pragma unroll
    for (int j = 0; j < 76; ++j) {
        const float s = v[j + 2];
        #pragma unroll
        for (int i = 0; i < 16; ++i) {
            const int t = j - i;
            if (t >= 0 && t < KS)
                acc[i] = fmaf(g.w[t], s, acc[i]);
        }
    }

    float* drow = out + ((size_t)bc * HH + y) * WW + X;
    #pragma unroll
    for (int i = 0; i < 4; ++i)
        *(float4*)(drow + 4 * i) = make_float4(acc[4*i], acc[4*i+1],
                                               acc[4*i+2], acc[4*i+3]);
}

// ---------------------------------------------------------------------------
// Vertical conv. Thread = 16 consecutive outputs of one column.
// Block 256 thr = 256 cols. Grid flat 6144, XCD-chunked so one XCD sweeps
// Y over a fixed (256-col, bc) strip -> halo re-reads are private-L2 hits.
// ---------------------------------------------------------------------------
__global__ __launch_bounds__(256) void vconv(const float* __restrict__ in,
                                             float* __restrict__ out, GW g) {
    const int f   = blockIdx.x;            // 0..6143
    const int c   = f & 7;                 // XCD
    const int idx = f >> 3;                // 0..767
    const int w0  = c * 768 + idx;         // work id, Y fastest
    const int Yt  = w0 & 63;
    const int r1  = w0 >> 6;
    const int xq  = r1 & 3;
    const int bc  = r1 >> 2;

    const int x = xq * 256 + threadIdx.x;
    const int Y = Yt * 16;                 // first output row

    const float* __restrict__ src = in + (size_t)bc * (HH * (size_t)WW);

    // stage the 76-row window (row base is wave-uniform -> SALU addressing)
    float v[76];
    #pragma unroll
    for (int j = 0; j < 76; ++j) {
        int gy = Y - HK + j;
        gy = min(max(gy, 0), HH - 1);      // replicate pad, wave-uniform
        v[j] = src[(size_t)gy * WW + x];
    }

    float acc[16];
    #pragma unroll
    for (int i = 0; i < 16; ++i) acc[i] = 0.f;

    #pragma unroll
    for (int j = 0; j < 76; ++j) {
        const float s = v[j];
        #pragma unroll
        for (int i = 0; i < 16; ++i) {
            const int t = j - i;
            if (t >= 0 && t < KS)
                acc[i] = fmaf(g.w[t], s, acc[i]);
        }
    }

    float* dst = out + (size_t)bc * (HH * (size_t)WW) + (size_t)Y * WW + x;
    #pragma unroll
    for (int i = 0; i < 16; ++i) dst[(size_t)i * WW] = acc[i];
}

// ---------------------------------------------------------------------------
static void fill_w(double sigma, GW* g) {
    double tmp[KS], s = 0.0;
    for (int k = 0; k < KS; ++k) {
        const double d = (double)(k - HK);
        tmp[k] = exp(-(d * d) / (2.0 * sigma * sigma));
        s += tmp[k];
    }
    for (int k = 0; k < KS; ++k) g->w[k] = (float)(tmp[k] / s);
}

extern "C" void kernel_launch(void* const* d_in, const int* in_sizes, int n_in,
                              void* d_out, int out_size, void* d_ws, size_t ws_size,
                              hipStream_t stream) {
    const float* input = (const float*)d_in[0];
    float* out = (float*)d_out;
    float* tmp = (float*)d_ws;                     // 96 MiB scratch

    GW g10, g20, g40;
    fill_w(10.0, &g10);
    fill_w(20.0, &g20);
    fill_w(40.0, &g40);

    const dim3 hb(256), hg(6144);          // flat, XCD-chunked decode
    const dim3 vb(256), vg(6144);

    hconv<<<hg, hb, 0, stream>>>(input, tmp, g10);
    vconv<<<vg, vb, 0, stream>>>(tmp, out, g10);
    hconv<<<hg, hb, 0, stream>>>(out, tmp, g20);
    vconv<<<vg, vb, 0, stream>>>(tmp, out, g20);
    hconv<<<hg, hb, 0, stream>>>(out, tmp, g40);
    vconv<<<vg, vb, 0, stream>>>(tmp, out, g40);
}